// Round 3
// baseline (304.405 us; speedup 1.0000x reference)
//
#include <hip/hip_runtime.h>
#include <stdint.h>
#include <stddef.h>

#define DIM   256
#define NH    8
#define HD    32
#define BATCH 16
#define NTOK  4096   // 64*64

typedef __attribute__((ext_vector_type(8))) short short8;
typedef __attribute__((ext_vector_type(4))) float f32x4;

__device__ __forceinline__ unsigned short f2bf(float x){
  unsigned u = __float_as_uint(x);
  u += 0x7fffu + ((u >> 16) & 1u);       // RNE
  return (unsigned short)(u >> 16);
}
__device__ __forceinline__ float bf2f(unsigned short h){
  return __uint_as_float(((unsigned)h) << 16);
}
__device__ __forceinline__ float elu1(float v){
  return (v > 0.f) ? (v + 1.f) : __expf(v);
}

// ---------------- P1: x [b][c][n] f32 -> x_t [b][n][c] bf16 ----------------
__global__ __launch_bounds__(256) void k_transpose_x(const float* __restrict__ x,
                                                     unsigned short* __restrict__ xt){
  __shared__ float tile[64][65];
  const int b = blockIdx.z, c0 = blockIdx.y * 64, n0 = blockIdx.x * 64;
  const float* xb = x + (size_t)b * DIM * NTOK;
  const int t = threadIdx.x;
  #pragma unroll
  for (int p = 0; p < 4; p++){
    int idx = t + p * 256;
    int row = idx >> 4;
    int col = (idx & 15) << 2;
    float4 v = *(const float4*)(xb + (size_t)(c0 + row) * NTOK + n0 + col);
    tile[row][col] = v.x; tile[row][col+1] = v.y; tile[row][col+2] = v.z; tile[row][col+3] = v.w;
  }
  __syncthreads();
  unsigned short* xtb = xt + (size_t)b * NTOK * DIM;
  #pragma unroll
  for (int p = 0; p < 4; p++){
    int idx = t + p * 256;
    int nl = idx >> 4;
    int cl = (idx & 15) << 2;
    ushort4 o;
    o.x = f2bf(tile[cl+0][nl]); o.y = f2bf(tile[cl+1][nl]);
    o.z = f2bf(tile[cl+2][nl]); o.w = f2bf(tile[cl+3][nl]);
    *(ushort4*)(xtb + (size_t)(n0 + nl) * DIM + c0 + cl) = o;
  }
}

// ---------------- P2: convert Wqkv to bf16 ----------------
__global__ __launch_bounds__(256) void k_convert_w(const float* __restrict__ wqkv,
                                                   unsigned short* __restrict__ wq_bf){
  int i = blockIdx.x * 256 + threadIdx.x;  // 49152 threads, 4 elems each
  float4 v = *(const float4*)(wqkv + (size_t)i * 4);
  ushort4 o = { f2bf(v.x), f2bf(v.y), f2bf(v.z), f2bf(v.w) };
  *(ushort4*)(wq_bf + (size_t)i * 4) = o;
}

// ---------------- K1: qkv GEMM, LDS-FREE K-loop. A=Wqkv rows(o), B=xt rows(n). D[o][n].
// Fragment loads go straight from global (fully coalesced: 16 rows x 64B per wave-load).
// No __syncthreads in K-loop -> no vmcnt(0) barrier drain; loads stay in flight.
// Epilogue: elu+1 (q,k), per-(n,head) normalize via shfl, LDS-bounce coalesced stores:
//  q-blocks  -> qn  [b][n][c] bf16 (normalized)
//  k/v-blocks-> kvT [b][row][n] bf16 (k rows 0..255 normalized, v rows 256..511 raw)
__global__ __launch_bounds__(256, 3) void k_qkv3(const unsigned short* __restrict__ wbf,
                                                 const unsigned short* __restrict__ xt,
                                                 unsigned short* __restrict__ qn,
                                                 unsigned short* __restrict__ kvT){
  __shared__ __align__(16) unsigned short sh[17408];  // epilogue bounce 128*136
  const int t = threadIdx.x;
  const int w = t >> 6, l = t & 63;
  const int t16 = l & 15, quad = l >> 4;
  const int wm = w >> 1, wn = w & 1;
  // swizzle: 6 o-tiles sharing one (nt,b) land on the same XCD within a 48-bid window
  const int bid = blockIdx.x;
  const int super = bid / 48;
  const int rem = bid - super * 48;
  const int m = rem >> 3, lx = rem & 7;
  const int g = super * 8 + lx;          // 0..511 : (nt, b)
  const int nt = g >> 4, b = g & 15;
  const int o0 = m * 128, n0 = nt * 128;

  const unsigned short* A  = wbf + (size_t)(o0 + wm*64) * DIM;                      // wave's 64 o-rows
  const unsigned short* Bp = xt + (size_t)b * NTOK * DIM + (size_t)(n0 + wn*64) * DIM; // wave's 64 n-rows

  f32x4 acc[4][4];
  #pragma unroll
  for (int i = 0; i < 4; i++)
    #pragma unroll
    for (int j = 0; j < 4; j++){ acc[i][j][0]=0.f; acc[i][j][1]=0.f; acc[i][j][2]=0.f; acc[i][j][3]=0.f; }

  #pragma unroll
  for (int kc = 0; kc < 8; kc++){
    const int ko = kc * 32 + quad * 8;
    short8 a[4], bb[4];
    #pragma unroll
    for (int i = 0; i < 4; i++) a[i]  = *(const short8*)(A  + (size_t)(i*16 + t16) * DIM + ko);
    #pragma unroll
    for (int j = 0; j < 4; j++) bb[j] = *(const short8*)(Bp + (size_t)(j*16 + t16) * DIM + ko);
    #pragma unroll
    for (int i = 0; i < 4; i++)
      #pragma unroll
      for (int j = 0; j < 4; j++)
        acc[i][j] = __builtin_amdgcn_mfma_f32_16x16x32_bf16(a[i], bb[j], acc[i][j], 0, 0, 0);
  }

  const bool isV = (o0 >= 512);
  const bool isQ = (o0 < 256);
  if (!isV){
    #pragma unroll
    for (int i = 0; i < 4; i++)
      #pragma unroll
      for (int j = 0; j < 4; j++)
        #pragma unroll
        for (int r = 0; r < 4; r++) acc[i][j][r] = elu1(acc[i][j][r]);
    float s[2][4];
    #pragma unroll
    for (int hi = 0; hi < 2; hi++)
      #pragma unroll
      for (int j = 0; j < 4; j++){
        float v = 0.f;
        #pragma unroll
        for (int ii = 0; ii < 2; ii++)
          #pragma unroll
          for (int r = 0; r < 4; r++) v += acc[hi*2 + ii][j][r];
        v += __shfl_xor(v, 16);
        v += __shfl_xor(v, 32);
        s[hi][j] = 1.0f / v;
      }
    #pragma unroll
    for (int i = 0; i < 4; i++)
      #pragma unroll
      for (int j = 0; j < 4; j++){
        float inv = s[i>>1][j];
        #pragma unroll
        for (int r = 0; r < 4; r++) acc[i][j][r] *= inv;
      }
  }

  // LDS bounce. q: tile[n_l][o_l]; k/v: tile[o_l][n_l]. stride 136 u16 (16B-aligned rows)
  if (isQ){
    #pragma unroll
    for (int i = 0; i < 4; i++)
      #pragma unroll
      for (int j = 0; j < 4; j++){
        int n_l = wn*64 + j*16 + t16;
        #pragma unroll
        for (int r = 0; r < 4; r++){
          int o_l = wm*64 + i*16 + quad*4 + r;
          sh[n_l*136 + o_l] = f2bf(acc[i][j][r]);
        }
      }
  } else {
    #pragma unroll
    for (int i = 0; i < 4; i++)
      #pragma unroll
      for (int j = 0; j < 4; j++){
        int n_l = wn*64 + j*16 + t16;
        #pragma unroll
        for (int r = 0; r < 4; r++){
          int o_l = wm*64 + i*16 + quad*4 + r;
          sh[o_l*136 + n_l] = f2bf(acc[i][j][r]);
        }
      }
  }
  __syncthreads();

  if (isQ){
    unsigned short* dst = qn + (size_t)b * NTOK * DIM;
    #pragma unroll
    for (int p = 0; p < 8; p++){
      int gg = t + p * 256;
      int n_l = gg >> 4, c = gg & 15;
      uint4 v = *(const uint4*)(sh + n_l*136 + c*8);
      *(uint4*)(dst + (size_t)(n0 + n_l) * DIM + o0 + c*8) = v;
    }
  } else {
    unsigned short* dst = kvT + (size_t)b * 512 * NTOK + (size_t)(o0 - 256) * NTOK;
    #pragma unroll
    for (int p = 0; p < 8; p++){
      int gg = t + p * 256;
      int o_l = gg >> 4, c = gg & 15;
      uint4 v = *(const uint4*)(sh + o_l*136 + c*8);
      *(uint4*)(dst + (size_t)o_l * NTOK + n0 + c*8) = v;
    }
  }
}

// ---------------- K2: kv partials via MFMA. kvT rows: k=[h*32+d], v=[256+h*32+e], n-contig.
// grid (8 nsplit, 8 h, 16 b), 4 waves/block, each wave K=128 chunk -> partial kv 32x32.
__global__ __launch_bounds__(256) void k_kv2(const unsigned short* __restrict__ kvT,
                                             float* __restrict__ kvp){
  const int t = threadIdx.x;
  const int w = t >> 6, l = t & 63;
  const int t16 = l & 15, quad = l >> 4;
  const int ns = blockIdx.x, h = blockIdx.y, b = blockIdx.z;
  const unsigned short* base = kvT + (size_t)b * 512 * NTOK;
  const int n_off = ns * 512 + w * 128;

  f32x4 acc[2][2];
  #pragma unroll
  for (int i = 0; i < 2; i++)
    #pragma unroll
    for (int j = 0; j < 2; j++){ acc[i][j][0]=0.f; acc[i][j][1]=0.f; acc[i][j][2]=0.f; acc[i][j][3]=0.f; }

  const unsigned short* krow0 = base + (size_t)(h*32 + t16) * NTOK;
  const unsigned short* krow1 = krow0 + (size_t)16 * NTOK;
  const unsigned short* vrow0 = base + (size_t)(256 + h*32 + t16) * NTOK;
  const unsigned short* vrow1 = vrow0 + (size_t)16 * NTOK;

  #pragma unroll
  for (int kk = 0; kk < 4; kk++){
    int n = n_off + kk*32 + quad*8;
    short8 a0 = *(const short8*)(krow0 + n);
    short8 a1 = *(const short8*)(krow1 + n);
    short8 b0 = *(const short8*)(vrow0 + n);
    short8 b1 = *(const short8*)(vrow1 + n);
    acc[0][0] = __builtin_amdgcn_mfma_f32_16x16x32_bf16(a0, b0, acc[0][0], 0, 0, 0);
    acc[0][1] = __builtin_amdgcn_mfma_f32_16x16x32_bf16(a0, b1, acc[0][1], 0, 0, 0);
    acc[1][0] = __builtin_amdgcn_mfma_f32_16x16x32_bf16(a1, b0, acc[1][0], 0, 0, 0);
    acc[1][1] = __builtin_amdgcn_mfma_f32_16x16x32_bf16(a1, b1, acc[1][1], 0, 0, 0);
  }
  float* dst = kvp + (size_t)(((b*8 + h)*32) + ns*4 + w) * 1024;
  #pragma unroll
  for (int ti = 0; ti < 2; ti++)
    #pragma unroll
    for (int tj = 0; tj < 2; tj++)
      #pragma unroll
      for (int r = 0; r < 4; r++)
        dst[(ti*16 + quad*4 + r)*32 + tj*16 + t16] = acc[ti][tj][r];
}

// ---------------- K3: reduce kv partials + fold Wproj: M[b][o][h*32+d] = sum_e Wp[o][h*32+e]*kv[d][e]
__global__ __launch_bounds__(256) void k_M(const float* __restrict__ kvp,
                                           const float* __restrict__ wproj,
                                           unsigned short* __restrict__ M){
  __shared__ float kvL[1024];
  __shared__ float wpL[8192];   // [o][e] 256x32
  const int t = threadIdx.x;
  const int h = blockIdx.x, b = blockIdx.y;
  const float* pbase = kvp + (size_t)((b*8 + h)*32) * 1024;
  {
    float4 a = {0.f,0.f,0.f,0.f};
    #pragma unroll
    for (int p = 0; p < 32; p++){
      float4 v = *(const float4*)(pbase + (size_t)p*1024 + t*4);
      a.x += v.x; a.y += v.y; a.z += v.z; a.w += v.w;
    }
    *(float4*)(kvL + t*4) = a;
  }
  #pragma unroll
  for (int p = 0; p < 8; p++){
    int idx = t + p * 256;          // float4 index over 256x32
    int o = idx >> 3, e4 = idx & 7;
    *(float4*)(wpL + o*32 + e4*4) = *(const float4*)(wproj + (size_t)o * DIM + h*32 + e4*4);
  }
  __syncthreads();
  float wr[32];
  #pragma unroll
  for (int e = 0; e < 32; e++) wr[e] = wpL[t*32 + e];
  unsigned short md[32];
  #pragma unroll
  for (int d = 0; d < 32; d++){
    float a = 0.f;
    #pragma unroll
    for (int e = 0; e < 32; e++) a += wr[e] * kvL[d*32 + e];
    md[d] = f2bf(a);
  }
  unsigned short* dst = M + (size_t)b * 65536 + (size_t)t * DIM + h*32;
  #pragma unroll
  for (int q = 0; q < 4; q++) *(uint4*)(dst + q*8) = *(const uint4*)(md + q*8);
}

// ---------------- K4: out GEMM, LDS-FREE. out[b][o][n] = sum_c M_b[o][c]*qn[b][n][c] + bproj[o] + x[b][o][n]
__global__ __launch_bounds__(256, 3) void k_out3(const unsigned short* __restrict__ M,
                                                 const unsigned short* __restrict__ qn,
                                                 const float* __restrict__ x,
                                                 const float* __restrict__ bproj,
                                                 float* __restrict__ out){
  const int t = threadIdx.x;
  const int w = t >> 6, l = t & 63;
  const int t16 = l & 15, quad = l >> 4;
  const int wm = w >> 1, wn = w & 1;
  // swizzle: 2 o-tiles sharing one (nt,b) on same XCD within 16 bids
  const int bid = blockIdx.x;
  const int super = bid >> 4;
  const int rem = bid & 15;
  const int m = rem >> 3, lx = rem & 7;
  const int g = super * 8 + lx;          // 0..511
  const int nt = g >> 4, b = g & 15;
  const int o0 = m * 128, n0 = nt * 128;

  const unsigned short* A  = M + (size_t)b * 65536 + (size_t)(o0 + wm*64) * DIM;
  const unsigned short* Bp = qn + (size_t)b * NTOK * DIM + (size_t)(n0 + wn*64) * DIM;

  f32x4 acc[4][4];
  #pragma unroll
  for (int i = 0; i < 4; i++)
    #pragma unroll
    for (int j = 0; j < 4; j++){ acc[i][j][0]=0.f; acc[i][j][1]=0.f; acc[i][j][2]=0.f; acc[i][j][3]=0.f; }

  #pragma unroll
  for (int kc = 0; kc < 8; kc++){
    const int ko = kc * 32 + quad * 8;
    short8 a[4], bb[4];
    #pragma unroll
    for (int i = 0; i < 4; i++) a[i]  = *(const short8*)(A  + (size_t)(i*16 + t16) * DIM + ko);
    #pragma unroll
    for (int j = 0; j < 4; j++) bb[j] = *(const short8*)(Bp + (size_t)(j*16 + t16) * DIM + ko);
    #pragma unroll
    for (int i = 0; i < 4; i++)
      #pragma unroll
      for (int j = 0; j < 4; j++)
        acc[i][j] = __builtin_amdgcn_mfma_f32_16x16x32_bf16(a[i], bb[j], acc[i][j], 0, 0, 0);
  }

  const float* xb = x + (size_t)b * DIM * NTOK;
  float* ob = out + (size_t)b * DIM * NTOK;
  #pragma unroll
  for (int i = 0; i < 4; i++){
    #pragma unroll
    for (int r = 0; r < 4; r++){
      int o = o0 + wm*64 + i*16 + quad*4 + r;
      float bias = bproj[o];
      #pragma unroll
      for (int j = 0; j < 4; j++){
        int n = n0 + wn*64 + j*16 + t16;
        float v = acc[i][j][r] + bias + xb[(size_t)o * NTOK + n];
        ob[(size_t)o * NTOK + n] = v;
      }
    }
  }
}

extern "C" void kernel_launch(void* const* d_in, const int* in_sizes, int n_in,
                              void* d_out, int out_size, void* d_ws, size_t ws_size,
                              hipStream_t stream){
  const float* x     = (const float*)d_in[0];
  const float* wqkv  = (const float*)d_in[1];
  const float* wproj = (const float*)d_in[2];
  const float* bproj = (const float*)d_in[3];
  float* out = (float*)d_out;
  char* ws = (char*)d_ws;

  // ws layout (~128.4 MiB):
  unsigned short* xt   = (unsigned short*)(ws);                        // 32 MiB (dead after k_qkv3)
  unsigned short* qn   = (unsigned short*)(ws + ((size_t)32 << 20));   // 32 MiB [b][n][256]
  unsigned short* kvT  = (unsigned short*)(ws + ((size_t)64 << 20));   // 64 MiB [b][512][4096]
  unsigned short* wqbf = (unsigned short*)(ws + ((size_t)128 << 20));  // 384 KiB
  float* kvp = (float*)(ws);                                           // 16 MiB, reuses xt region
  unsigned short* M = (unsigned short*)(ws + ((size_t)16 << 20));      // 2 MiB, reuses xt region

  k_transpose_x<<<dim3(64, 4, 16), 256, 0, stream>>>(x, xt);
  k_convert_w  <<<dim3(192), 256, 0, stream>>>(wqkv, wqbf);
  k_qkv3       <<<dim3(3072), 256, 0, stream>>>(wqbf, xt, qn, kvT);
  k_kv2        <<<dim3(8, 8, 16), 256, 0, stream>>>(kvT, kvp);
  k_M          <<<dim3(8, 16), 256, 0, stream>>>(kvp, wproj, M);
  k_out3       <<<dim3(1024), 256, 0, stream>>>(M, qn, x, bproj, out);
}

// Round 4
// 251.524 us; speedup vs baseline: 1.2102x; 1.2102x over previous
//
#include <hip/hip_runtime.h>
#include <stdint.h>
#include <stddef.h>

#define DIM   256
#define NH    8
#define HD    32
#define BATCH 16
#define NTOK  4096   // 64*64

typedef __attribute__((ext_vector_type(8))) short short8;
typedef __attribute__((ext_vector_type(4))) float f32x4;

__device__ __forceinline__ unsigned short f2bf(float x){
  unsigned u = __float_as_uint(x);
  u += 0x7fffu + ((u >> 16) & 1u);       // RNE
  return (unsigned short)(u >> 16);
}
__device__ __forceinline__ float elu1(float v){
  return (v > 0.f) ? (v + 1.f) : __expf(v);
}
// async global->LDS, 16B per lane. lds dest = wave-uniform base + lane*16.
__device__ __forceinline__ void gload_lds16(const void* g, void* lds){
  __builtin_amdgcn_global_load_lds(
      (const __attribute__((address_space(1))) unsigned int*)g,
      (__attribute__((address_space(3))) unsigned int*)lds, 16, 0, 0);
}

// ---------------- P1: x [b][c][n] f32 -> x_t [b][n][c] bf16 ----------------
__global__ __launch_bounds__(256) void k_transpose_x(const float* __restrict__ x,
                                                     unsigned short* __restrict__ xt){
  __shared__ float tile[64][65];
  const int b = blockIdx.z, c0 = blockIdx.y * 64, n0 = blockIdx.x * 64;
  const float* xb = x + (size_t)b * DIM * NTOK;
  const int t = threadIdx.x;
  #pragma unroll
  for (int p = 0; p < 4; p++){
    int idx = t + p * 256;
    int row = idx >> 4;
    int col = (idx & 15) << 2;
    float4 v = *(const float4*)(xb + (size_t)(c0 + row) * NTOK + n0 + col);
    tile[row][col] = v.x; tile[row][col+1] = v.y; tile[row][col+2] = v.z; tile[row][col+3] = v.w;
  }
  __syncthreads();
  unsigned short* xtb = xt + (size_t)b * NTOK * DIM;
  #pragma unroll
  for (int p = 0; p < 4; p++){
    int idx = t + p * 256;
    int nl = idx >> 4;
    int cl = (idx & 15) << 2;
    ushort4 o;
    o.x = f2bf(tile[cl+0][nl]); o.y = f2bf(tile[cl+1][nl]);
    o.z = f2bf(tile[cl+2][nl]); o.w = f2bf(tile[cl+3][nl]);
    *(ushort4*)(xtb + (size_t)(n0 + nl) * DIM + c0 + cl) = o;
  }
}

// ---------------- P2: convert Wqkv to bf16, PERMUTED row layout ----------------
// dest rows: [0..255]=q (unchanged). Then 4 tiles of 128: tile p = [k heads 2p,2p+1 (64 rows) | v heads 2p,2p+1 (64 rows)]
__global__ __launch_bounds__(256) void k_convert_w(const float* __restrict__ wqkv,
                                                   unsigned short* __restrict__ wq_bf){
  int i = blockIdx.x * 256 + threadIdx.x;  // 49152 threads: 768 rows x 64 groups of 4c
  int row = i >> 6;
  int c4 = (i & 63) * 4;
  int dst;
  if (row < 256)      dst = row;
  else if (row < 512){ int p = (row - 256) >> 6; int s = (row - 256) & 63; dst = 256 + p*128 + s; }
  else               { int p = (row - 512) >> 6; int s = (row - 512) & 63; dst = 256 + p*128 + 64 + s; }
  float4 v = *(const float4*)(wqkv + (size_t)row * DIM + c4);
  ushort4 o = { f2bf(v.x), f2bf(v.y), f2bf(v.z), f2bf(v.w) };
  *(ushort4*)(wq_bf + (size_t)dst * DIM + c4) = o;
}

// ---------------- K1: qkv GEMM (LDS-staged, swizzled) + fused kv epilogue ----------------
// Block tile 128(o) x 128(n), D[o][n]. o-tiles 0,1 = q -> normalize, write qn [b][n][c].
// o-tiles 2..5 = [k | v] for head pair p: normalize k in-register, bounce k,v to LDS,
// compute per-head 32x32 kv partial over this block's 128 tokens via MFMA -> kvp[b][h][nt].
__global__ __launch_bounds__(256) void k_qkv4(const unsigned short* __restrict__ wbf,
                                              const unsigned short* __restrict__ xt,
                                              unsigned short* __restrict__ qn,
                                              float* __restrict__ kvp){
  __shared__ __align__(16) unsigned short sh[17408];  // staging 16384 u16; epilogue bounce 128*136
  unsigned short* As = sh;          // 16 slabs * 512 u16
  unsigned short* Bs = sh + 8192;
  const int t = threadIdx.x;
  const int w = t >> 6, l = t & 63;
  const int t16 = l & 15, quad = l >> 4;
  const int wm = w >> 1, wn = w & 1;
  // swizzle: 6 o-tiles sharing one (nt,b) land on the same XCD within a 48-bid window
  const int bid = blockIdx.x;
  const int super = bid / 48;
  const int rem = bid - super * 48;
  const int m = rem >> 3, lx = rem & 7;
  const int g = super * 8 + lx;          // 0..511 : (nt, b)
  const int nt = g >> 4, b = g & 15;
  const int o0 = m * 128, n0 = nt * 128;
  const unsigned short* A = wbf;                          // [768][256] permuted
  const unsigned short* B = xt + (size_t)b * NTOK * DIM;  // [n][256]

  f32x4 acc[4][4];
  #pragma unroll
  for (int i = 0; i < 4; i++)
    #pragma unroll
    for (int j = 0; j < 4; j++){ acc[i][j][0]=0.f; acc[i][j][1]=0.f; acc[i][j][2]=0.f; acc[i][j][3]=0.f; }

  for (int k0 = 0; k0 < 256; k0 += 64){
    __syncthreads();
    #pragma unroll
    for (int j = 0; j < 4; j++){
      int s = w * 4 + j;             // 0..15
      int tile = s >> 1, kk = s & 1;
      gload_lds16(A + (size_t)(o0 + tile*16 + t16) * DIM + k0 + kk*32 + quad*8, As + s * 512);
      gload_lds16(B + (size_t)(n0 + tile*16 + t16) * DIM + k0 + kk*32 + quad*8, Bs + s * 512);
    }
    __syncthreads();
    #pragma unroll
    for (int kk = 0; kk < 2; kk++){
      short8 a[4], bb[4];
      #pragma unroll
      for (int i = 0; i < 4; i++) a[i]  = *(const short8*)(As + ((wm*4 + i)*2 + kk) * 512 + l * 8);
      #pragma unroll
      for (int j = 0; j < 4; j++) bb[j] = *(const short8*)(Bs + ((wn*4 + j)*2 + kk) * 512 + l * 8);
      #pragma unroll
      for (int i = 0; i < 4; i++)
        #pragma unroll
        for (int j = 0; j < 4; j++)
          acc[i][j] = __builtin_amdgcn_mfma_f32_16x16x32_bf16(a[i], bb[j], acc[i][j], 0, 0, 0);
    }
  }
  __syncthreads();   // staging reads done; sh reused for epilogue bounce

  const bool isQ = (o0 < 256);
  // q tiles: all rows get elu+norm. k/v tiles: only wm==0 waves (k rows); v stays raw.
  if (isQ || wm == 0){
    #pragma unroll
    for (int i = 0; i < 4; i++)
      #pragma unroll
      for (int j = 0; j < 4; j++)
        #pragma unroll
        for (int r = 0; r < 4; r++) acc[i][j][r] = elu1(acc[i][j][r]);
    float s[2][4];   // per (head-local hi=i>>1, col j) inverse sums
    #pragma unroll
    for (int hi = 0; hi < 2; hi++)
      #pragma unroll
      for (int j = 0; j < 4; j++){
        float v = 0.f;
        #pragma unroll
        for (int ii = 0; ii < 2; ii++)
          #pragma unroll
          for (int r = 0; r < 4; r++) v += acc[hi*2 + ii][j][r];
        v += __shfl_xor(v, 16);
        v += __shfl_xor(v, 32);
        s[hi][j] = 1.0f / v;
      }
    #pragma unroll
    for (int i = 0; i < 4; i++)
      #pragma unroll
      for (int j = 0; j < 4; j++){
        float inv = s[i>>1][j];
        #pragma unroll
        for (int r = 0; r < 4; r++) acc[i][j][r] *= inv;
      }
  }

  // LDS bounce. q: tile[n_l][o_l]; k/v: tile[o_l][n_l]. stride 136 u16 (rows 272B, 16B-aligned)
  if (isQ){
    #pragma unroll
    for (int i = 0; i < 4; i++)
      #pragma unroll
      for (int j = 0; j < 4; j++){
        int n_l = wn*64 + j*16 + t16;
        #pragma unroll
        for (int r = 0; r < 4; r++){
          int o_l = wm*64 + i*16 + quad*4 + r;
          sh[n_l*136 + o_l] = f2bf(acc[i][j][r]);
        }
      }
  } else {
    #pragma unroll
    for (int i = 0; i < 4; i++)
      #pragma unroll
      for (int j = 0; j < 4; j++){
        int n_l = wn*64 + j*16 + t16;
        #pragma unroll
        for (int r = 0; r < 4; r++){
          int o_l = wm*64 + i*16 + quad*4 + r;
          sh[o_l*136 + n_l] = f2bf(acc[i][j][r]);
        }
      }
  }
  __syncthreads();

  if (isQ){
    unsigned short* dst = qn + (size_t)b * NTOK * DIM;
    #pragma unroll
    for (int p = 0; p < 8; p++){
      int gg = t + p * 256;
      int n_l = gg >> 4, c = gg & 15;
      uint4 v = *(const uint4*)(sh + n_l*136 + c*8);
      *(uint4*)(dst + (size_t)(n0 + n_l) * DIM + o0 + c*8) = v;
    }
  } else {
    // kv partial: head pair p, wave -> (head-local hl, e-half eh). K = 128 tokens (this block).
    const int p = (o0 >> 7) - 2;         // 0..3
    const int hl = w >> 1, eh = w & 1;
    f32x4 kvacc[2];
    kvacc[0][0]=0.f; kvacc[0][1]=0.f; kvacc[0][2]=0.f; kvacc[0][3]=0.f;
    kvacc[1][0]=0.f; kvacc[1][1]=0.f; kvacc[1][2]=0.f; kvacc[1][3]=0.f;
    const unsigned short* kbase = sh + (hl*32) * 136;                 // k rows (normalized)
    const unsigned short* vbase = sh + (64 + hl*32 + eh*16) * 136;    // v rows (raw)
    #pragma unroll
    for (int kk = 0; kk < 4; kk++){
      int nn = kk*32 + quad*8;
      short8 bfrag = *(const short8*)(vbase + t16*136 + nn);
      #pragma unroll
      for (int ti = 0; ti < 2; ti++){
        short8 afrag = *(const short8*)(kbase + (ti*16 + t16)*136 + nn);
        kvacc[ti] = __builtin_amdgcn_mfma_f32_16x16x32_bf16(afrag, bfrag, kvacc[ti], 0, 0, 0);
      }
    }
    // store partial: kvp[b][h][nt][d*32+e], d = ti*16+quad*4+r, e = eh*16+t16
    float* dst = kvp + ((size_t)(b*8 + p*2 + hl) * 32 + nt) * 1024;
    #pragma unroll
    for (int ti = 0; ti < 2; ti++)
      #pragma unroll
      for (int r = 0; r < 4; r++)
        dst[(ti*16 + quad*4 + r)*32 + eh*16 + t16] = kvacc[ti][r];
  }
}

// ---------------- K3: reduce kv partials + fold Wproj: M[b][o][h*32+d] = sum_e Wp[o][h*32+e]*kv[d][e]
__global__ __launch_bounds__(256) void k_M(const float* __restrict__ kvp,
                                           const float* __restrict__ wproj,
                                           unsigned short* __restrict__ M){
  __shared__ float kvL[1024];
  __shared__ float wpL[8192];   // [o][e] 256x32
  const int t = threadIdx.x;
  const int h = blockIdx.x, b = blockIdx.y;
  const float* pbase = kvp + (size_t)((b*8 + h)*32) * 1024;
  {
    float4 a = {0.f,0.f,0.f,0.f};
    #pragma unroll
    for (int p = 0; p < 32; p++){
      float4 v = *(const float4*)(pbase + (size_t)p*1024 + t*4);
      a.x += v.x; a.y += v.y; a.z += v.z; a.w += v.w;
    }
    *(float4*)(kvL + t*4) = a;
  }
  #pragma unroll
  for (int p = 0; p < 8; p++){
    int idx = t + p * 256;          // float4 index over 256x32
    int o = idx >> 3, e4 = idx & 7;
    *(float4*)(wpL + o*32 + e4*4) = *(const float4*)(wproj + (size_t)o * DIM + h*32 + e4*4);
  }
  __syncthreads();
  float wr[32];
  #pragma unroll
  for (int e = 0; e < 32; e++) wr[e] = wpL[t*32 + e];
  unsigned short md[32];
  #pragma unroll
  for (int d = 0; d < 32; d++){
    float a = 0.f;
    #pragma unroll
    for (int e = 0; e < 32; e++) a += wr[e] * kvL[d*32 + e];
    md[d] = f2bf(a);
  }
  unsigned short* dst = M + (size_t)b * 65536 + (size_t)t * DIM + h*32;
  #pragma unroll
  for (int q = 0; q < 4; q++) *(uint4*)(dst + q*8) = *(const uint4*)(md + q*8);
}

// ---------------- K4: out GEMM (LDS-staged, swizzled). out[b][o][n] = sum_c M_b[o][c]*qn[b][n][c] + bproj[o] + x
__global__ __launch_bounds__(256) void k_out4(const unsigned short* __restrict__ M,
                                              const unsigned short* __restrict__ qn,
                                              const float* __restrict__ x,
                                              const float* __restrict__ bproj,
                                              float* __restrict__ out){
  __shared__ __align__(16) unsigned short As[8192];
  __shared__ __align__(16) unsigned short Bs[8192];
  const int t = threadIdx.x;
  const int w = t >> 6, l = t & 63;
  const int t16 = l & 15, quad = l >> 4;
  const int wm = w >> 1, wn = w & 1;
  // swizzle: 2 o-tiles sharing one (nt,b) on same XCD within 16 bids
  const int bid = blockIdx.x;
  const int super = bid >> 4;
  const int rem = bid & 15;
  const int m = rem >> 3, lx = rem & 7;
  const int g = super * 8 + lx;          // 0..511
  const int nt = g >> 4, b = g & 15;
  const int o0 = m * 128, n0 = nt * 128;
  const unsigned short* A = M + (size_t)b * 65536;        // [256][256]
  const unsigned short* B = qn + (size_t)b * NTOK * DIM;  // [n][256]

  f32x4 acc[4][4];
  #pragma unroll
  for (int i = 0; i < 4; i++)
    #pragma unroll
    for (int j = 0; j < 4; j++){ acc[i][j][0]=0.f; acc[i][j][1]=0.f; acc[i][j][2]=0.f; acc[i][j][3]=0.f; }

  for (int k0 = 0; k0 < 256; k0 += 64){
    __syncthreads();
    #pragma unroll
    for (int j = 0; j < 4; j++){
      int s = w * 4 + j;
      int tile = s >> 1, kk = s & 1;
      gload_lds16(A + (size_t)(o0 + tile*16 + t16) * DIM + k0 + kk*32 + quad*8, As + s * 512);
      gload_lds16(B + (size_t)(n0 + tile*16 + t16) * DIM + k0 + kk*32 + quad*8, Bs + s * 512);
    }
    __syncthreads();
    #pragma unroll
    for (int kk = 0; kk < 2; kk++){
      short8 a[4], bb[4];
      #pragma unroll
      for (int i = 0; i < 4; i++) a[i]  = *(const short8*)(As + ((wm*4 + i)*2 + kk) * 512 + l * 8);
      #pragma unroll
      for (int j = 0; j < 4; j++) bb[j] = *(const short8*)(Bs + ((wn*4 + j)*2 + kk) * 512 + l * 8);
      #pragma unroll
      for (int i = 0; i < 4; i++)
        #pragma unroll
        for (int j = 0; j < 4; j++)
          acc[i][j] = __builtin_amdgcn_mfma_f32_16x16x32_bf16(a[i], bb[j], acc[i][j], 0, 0, 0);
    }
  }

  const float* xb = x + (size_t)b * DIM * NTOK;
  float* ob = out + (size_t)b * DIM * NTOK;
  #pragma unroll
  for (int i = 0; i < 4; i++){
    #pragma unroll
    for (int r = 0; r < 4; r++){
      int o = o0 + wm*64 + i*16 + quad*4 + r;
      float bias = bproj[o];
      #pragma unroll
      for (int j = 0; j < 4; j++){
        int n = n0 + wn*64 + j*16 + t16;
        float v = acc[i][j][r] + bias + xb[(size_t)o * NTOK + n];
        ob[(size_t)o * NTOK + n] = v;
      }
    }
  }
}

extern "C" void kernel_launch(void* const* d_in, const int* in_sizes, int n_in,
                              void* d_out, int out_size, void* d_ws, size_t ws_size,
                              hipStream_t stream){
  const float* x     = (const float*)d_in[0];
  const float* wqkv  = (const float*)d_in[1];
  const float* wproj = (const float*)d_in[2];
  const float* bproj = (const float*)d_in[3];
  float* out = (float*)d_out;
  char* ws = (char*)d_ws;

  // ws layout (~82.4 MiB):
  unsigned short* xt   = (unsigned short*)(ws);                        // 32 MiB [b][n][256]
  unsigned short* qn   = (unsigned short*)(ws + ((size_t)32 << 20));   // 32 MiB [b][n][256]
  float* kvp           = (float*)(ws + ((size_t)64 << 20));            // 16 MiB [b][h][nt32][1024]
  unsigned short* M    = (unsigned short*)(ws + ((size_t)80 << 20));   // 2 MiB [b][256][256]
  unsigned short* wqbf = (unsigned short*)(ws + ((size_t)82 << 20));   // 384 KiB permuted

  k_transpose_x<<<dim3(64, 4, 16), 256, 0, stream>>>(x, xt);
  k_convert_w  <<<dim3(192), 256, 0, stream>>>(wqkv, wqbf);
  k_qkv4       <<<dim3(3072), 256, 0, stream>>>(wqbf, xt, qn, kvp);
  k_M          <<<dim3(8, 16), 256, 0, stream>>>(kvp, wproj, M);
  k_out4       <<<dim3(1024), 256, 0, stream>>>(M, qn, x, bproj, out);
}

// Round 5
// 229.913 us; speedup vs baseline: 1.3240x; 1.0940x over previous
//
#include <hip/hip_runtime.h>
#include <stdint.h>
#include <stddef.h>

#define DIM   256
#define NH    8
#define HD    32
#define BATCH 16
#define NTOK  4096   // 64*64

typedef __attribute__((ext_vector_type(8))) short short8;
typedef __attribute__((ext_vector_type(4))) float f32x4;

__device__ __forceinline__ unsigned short f2bf(float x){
  unsigned u = __float_as_uint(x);
  u += 0x7fffu + ((u >> 16) & 1u);       // RNE
  return (unsigned short)(u >> 16);
}
__device__ __forceinline__ float elu1(float v){
  return (v > 0.f) ? (v + 1.f) : __expf(v);
}
// async global->LDS, 16B per lane. lds dest = wave-uniform base + lane*16.
__device__ __forceinline__ void gload_lds16(const void* g, void* lds){
  __builtin_amdgcn_global_load_lds(
      (const __attribute__((address_space(1))) unsigned int*)g,
      (__attribute__((address_space(3))) unsigned int*)lds, 16, 0, 0);
}

// ---------------- P1: x [b][c][n] f32 -> x_t [b][n][c] bf16 ----------------
__global__ __launch_bounds__(256) void k_transpose_x(const float* __restrict__ x,
                                                     unsigned short* __restrict__ xt){
  __shared__ float tile[64][65];
  const int b = blockIdx.z, c0 = blockIdx.y * 64, n0 = blockIdx.x * 64;
  const float* xb = x + (size_t)b * DIM * NTOK;
  const int t = threadIdx.x;
  #pragma unroll
  for (int p = 0; p < 4; p++){
    int idx = t + p * 256;
    int row = idx >> 4;
    int col = (idx & 15) << 2;
    float4 v = *(const float4*)(xb + (size_t)(c0 + row) * NTOK + n0 + col);
    tile[row][col] = v.x; tile[row][col+1] = v.y; tile[row][col+2] = v.z; tile[row][col+3] = v.w;
  }
  __syncthreads();
  unsigned short* xtb = xt + (size_t)b * NTOK * DIM;
  #pragma unroll
  for (int p = 0; p < 4; p++){
    int idx = t + p * 256;
    int nl = idx >> 4;
    int cl = (idx & 15) << 2;
    ushort4 o;
    o.x = f2bf(tile[cl+0][nl]); o.y = f2bf(tile[cl+1][nl]);
    o.z = f2bf(tile[cl+2][nl]); o.w = f2bf(tile[cl+3][nl]);
    *(ushort4*)(xtb + (size_t)(n0 + nl) * DIM + c0 + cl) = o;
  }
}

// ---------------- P2: convert Wqkv to bf16, PERMUTED row layout ----------------
// dest rows: [0..255]=q. Then 4 tiles of 128: tile p = [k heads 2p,2p+1 | v heads 2p,2p+1]
__global__ __launch_bounds__(256) void k_convert_w(const float* __restrict__ wqkv,
                                                   unsigned short* __restrict__ wq_bf){
  int i = blockIdx.x * 256 + threadIdx.x;  // 49152 threads: 768 rows x 64 groups of 4c
  int row = i >> 6;
  int c4 = (i & 63) * 4;
  int dst;
  if (row < 256)      dst = row;
  else if (row < 512){ int p = (row - 256) >> 6; int s = (row - 256) & 63; dst = 256 + p*128 + s; }
  else               { int p = (row - 512) >> 6; int s = (row - 512) & 63; dst = 256 + p*128 + 64 + s; }
  float4 v = *(const float4*)(wqkv + (size_t)row * DIM + c4);
  ushort4 o = { f2bf(v.x), f2bf(v.y), f2bf(v.z), f2bf(v.w) };
  *(ushort4*)(wq_bf + (size_t)dst * DIM + c4) = o;
}

// ---------------- K1: qkv GEMM, 512 threads (8 waves, wave-tile 32x64) + fused kv epilogue ----------------
// Block tile 128(o) x 128(n). o-tiles 0,1 = q -> normalize, write qn [b][n][c].
// o-tiles 2..5 = [k(64 rows) | v(64 rows)] head pair p: k normalized in-register,
// bounce k,v to LDS [o][n], per-head 32x32 kv partial via MFMA -> kvp[b][h][nt].
__global__ __launch_bounds__(512, 4) void k_qkv5(const unsigned short* __restrict__ wbf,
                                                 const unsigned short* __restrict__ xt,
                                                 unsigned short* __restrict__ qn,
                                                 float* __restrict__ kvp){
  __shared__ __align__(16) unsigned short sh[17408];  // staging 32KB (32 slabs*512u16); bounce 128*136
  unsigned short* As = sh;          // slabs 0..15 (W rows)
  unsigned short* Bs = sh + 8192;   // slabs 0..15 (x rows)
  const int t = threadIdx.x;
  const int w = t >> 6, l = t & 63;
  const int t16 = l & 15, quad = l >> 4;
  const int wm = w >> 1, wn = w & 1;    // wm 0..3 (o-quarter), wn 0..1 (n-half)
  // swizzle: 6 o-tiles sharing one (nt,b) in a 48-bid window (same XCD)
  const int bid = blockIdx.x;
  const int super = bid / 48;
  const int rem = bid - super * 48;
  const int m = rem >> 3, lx = rem & 7;
  const int g = super * 8 + lx;          // 0..511 : (nt, b)
  const int nt = g >> 4, b = g & 15;
  const int o0 = m * 128, n0 = nt * 128;
  const unsigned short* A = wbf;                          // [768][256] permuted
  const unsigned short* B = xt + (size_t)b * NTOK * DIM;  // [n][256]

  f32x4 acc[2][4];   // i over o (2x16), j over n (4x16)
  #pragma unroll
  for (int i = 0; i < 2; i++)
    #pragma unroll
    for (int j = 0; j < 4; j++){ acc[i][j][0]=0.f; acc[i][j][1]=0.f; acc[i][j][2]=0.f; acc[i][j][3]=0.f; }

  for (int k0 = 0; k0 < 256; k0 += 64){
    __syncthreads();
    #pragma unroll
    for (int s4 = 0; s4 < 4; s4++){
      int s = w * 4 + s4;            // 0..31
      int sl = s & 15;
      int tile = sl >> 1, kk = sl & 1;
      const unsigned short* src = (s < 16)
          ? (A + (size_t)(o0 + tile*16 + t16) * DIM + k0 + kk*32 + quad*8)
          : (B + (size_t)(n0 + tile*16 + t16) * DIM + k0 + kk*32 + quad*8);
      gload_lds16(src, sh + s * 512);
    }
    __syncthreads();
    #pragma unroll
    for (int kk = 0; kk < 2; kk++){
      short8 a[2], bb[4];
      #pragma unroll
      for (int i = 0; i < 2; i++) a[i]  = *(const short8*)(As + ((wm*2 + i)*2 + kk) * 512 + l * 8);
      #pragma unroll
      for (int j = 0; j < 4; j++) bb[j] = *(const short8*)(Bs + ((wn*4 + j)*2 + kk) * 512 + l * 8);
      #pragma unroll
      for (int i = 0; i < 2; i++)
        #pragma unroll
        for (int j = 0; j < 4; j++)
          acc[i][j] = __builtin_amdgcn_mfma_f32_16x16x32_bf16(a[i], bb[j], acc[i][j], 0, 0, 0);
    }
  }
  __syncthreads();   // staging reads done; sh reused for epilogue bounce

  const bool isQ = (o0 < 256);
  // q tiles: all waves normalize (wave = one head's 32 rows). k/v tiles: wm<2 waves = k rows.
  if (isQ || wm < 2){
    #pragma unroll
    for (int i = 0; i < 2; i++)
      #pragma unroll
      for (int j = 0; j < 4; j++)
        #pragma unroll
        for (int r = 0; r < 4; r++) acc[i][j][r] = elu1(acc[i][j][r]);
    float s[4];
    #pragma unroll
    for (int j = 0; j < 4; j++){
      float v = 0.f;
      #pragma unroll
      for (int i = 0; i < 2; i++)
        #pragma unroll
        for (int r = 0; r < 4; r++) v += acc[i][j][r];
      v += __shfl_xor(v, 16);
      v += __shfl_xor(v, 32);
      s[j] = 1.0f / v;
    }
    #pragma unroll
    for (int i = 0; i < 2; i++)
      #pragma unroll
      for (int j = 0; j < 4; j++){
        float inv = s[j];
        #pragma unroll
        for (int r = 0; r < 4; r++) acc[i][j][r] *= inv;
      }
  }

  if (isQ){
    // bounce [n_l][o_l] stride 136, packed b64 (r runs along o_l)
    #pragma unroll
    for (int i = 0; i < 2; i++)
      #pragma unroll
      for (int j = 0; j < 4; j++){
        int n_l = wn*64 + j*16 + t16;
        int o_l0 = wm*32 + i*16 + quad*4;
        ushort4 pk = { f2bf(acc[i][j][0]), f2bf(acc[i][j][1]),
                       f2bf(acc[i][j][2]), f2bf(acc[i][j][3]) };
        *(ushort4*)(sh + n_l*136 + o_l0) = pk;
      }
    __syncthreads();
    unsigned short* dst = qn + (size_t)b * NTOK * DIM;
    #pragma unroll
    for (int p = 0; p < 4; p++){
      int gg = t + p * 512;
      int n_l = gg >> 4, c = gg & 15;
      uint4 v = *(const uint4*)(sh + n_l*136 + c*8);
      *(uint4*)(dst + (size_t)(n0 + n_l) * DIM + o0 + c*8) = v;
    }
  } else {
    // bounce [o_l][n_l] stride 136 (scalar; K-contiguous along n for the kv MFMA)
    #pragma unroll
    for (int i = 0; i < 2; i++)
      #pragma unroll
      for (int j = 0; j < 4; j++){
        int n_l = wn*64 + j*16 + t16;
        #pragma unroll
        for (int r = 0; r < 4; r++){
          int o_l = wm*32 + i*16 + quad*4 + r;
          sh[o_l*136 + n_l] = f2bf(acc[i][j][r]);
        }
      }
    __syncthreads();
    // kv partial over this block's 128 tokens. wave -> (hl, dh, eh)
    const int p = (o0 >> 7) - 2;          // 0..3
    const int hl = w >> 2, dh = (w >> 1) & 1, eh = w & 1;
    f32x4 kvacc;
    kvacc[0]=0.f; kvacc[1]=0.f; kvacc[2]=0.f; kvacc[3]=0.f;
    const unsigned short* kbase = sh + (hl*32 + dh*16) * 136;        // normalized k rows
    const unsigned short* vbase = sh + (64 + hl*32 + eh*16) * 136;   // raw v rows
    #pragma unroll
    for (int kk = 0; kk < 4; kk++){
      int nn = kk*32 + quad*8;
      short8 afrag = *(const short8*)(kbase + t16*136 + nn);
      short8 bfrag = *(const short8*)(vbase + t16*136 + nn);
      kvacc = __builtin_amdgcn_mfma_f32_16x16x32_bf16(afrag, bfrag, kvacc, 0, 0, 0);
    }
    float* dst = kvp + ((size_t)(b*8 + p*2 + hl) * 32 + nt) * 1024;
    #pragma unroll
    for (int r = 0; r < 4; r++)
      dst[(dh*16 + quad*4 + r)*32 + eh*16 + t16] = kvacc[r];
  }
}

// ---------------- K3: reduce kv partials + fold Wproj: M[b][o][h*32+d] = sum_e Wp[o][h*32+e]*kv[d][e]
__global__ __launch_bounds__(256) void k_M(const float* __restrict__ kvp,
                                           const float* __restrict__ wproj,
                                           unsigned short* __restrict__ M){
  __shared__ float kvL[1024];
  __shared__ float wpL[8192];   // [o][e] 256x32
  const int t = threadIdx.x;
  const int h = blockIdx.x, b = blockIdx.y;
  const float* pbase = kvp + (size_t)((b*8 + h)*32) * 1024;
  {
    float4 a = {0.f,0.f,0.f,0.f};
    #pragma unroll
    for (int p = 0; p < 32; p++){
      float4 v = *(const float4*)(pbase + (size_t)p*1024 + t*4);
      a.x += v.x; a.y += v.y; a.z += v.z; a.w += v.w;
    }
    *(float4*)(kvL + t*4) = a;
  }
  #pragma unroll
  for (int p = 0; p < 8; p++){
    int idx = t + p * 256;          // float4 index over 256x32
    int o = idx >> 3, e4 = idx & 7;
    *(float4*)(wpL + o*32 + e4*4) = *(const float4*)(wproj + (size_t)o * DIM + h*32 + e4*4);
  }
  __syncthreads();
  float wr[32];
  #pragma unroll
  for (int e = 0; e < 32; e++) wr[e] = wpL[t*32 + e];
  unsigned short md[32];
  #pragma unroll
  for (int d = 0; d < 32; d++){
    float a = 0.f;
    #pragma unroll
    for (int e = 0; e < 32; e++) a += wr[e] * kvL[d*32 + e];
    md[d] = f2bf(a);
  }
  unsigned short* dst = M + (size_t)b * 65536 + (size_t)t * DIM + h*32;
  #pragma unroll
  for (int q = 0; q < 4; q++) *(uint4*)(dst + q*8) = *(const uint4*)(md + q*8);
}

// ---------------- K4: out GEMM, FLIPPED operands (A=qn n-rows, B=M o-rows) ----------------
// D[row=quad*4+r -> n][col=t16 -> o]: per-lane 4 consecutive n => float4 epilogue, no bounce.
__global__ __launch_bounds__(512, 4) void k_out5(const unsigned short* __restrict__ M,
                                                 const unsigned short* __restrict__ qn,
                                                 const float* __restrict__ x,
                                                 const float* __restrict__ bproj,
                                                 float* __restrict__ out){
  __shared__ __align__(16) unsigned short As[8192];  // qn slabs (n rows)
  __shared__ __align__(16) unsigned short Bs[8192];  // M  slabs (o rows)
  const int t = threadIdx.x;
  const int w = t >> 6, l = t & 63;
  const int t16 = l & 15, quad = l >> 4;
  const int wm = w >> 1, wn = w & 1;     // wm 0..3 (n-quarter), wn 0..1 (o-half)
  // swizzle: 2 o-tiles sharing one (nt,b) within a 16-bid window
  const int bid = blockIdx.x;
  const int super = bid >> 4;
  const int rem = bid & 15;
  const int m = rem >> 3, lx = rem & 7;
  const int g = super * 8 + lx;          // 0..511
  const int nt = g >> 4, b = g & 15;
  const int o0 = m * 128, n0 = nt * 128;
  const unsigned short* A = qn + (size_t)b * NTOK * DIM;  // [n][256]
  const unsigned short* Bm = M + (size_t)b * 65536;       // [256][256]

  f32x4 acc[2][4];   // i over n (2x16), j over o (4x16)
  #pragma unroll
  for (int i = 0; i < 2; i++)
    #pragma unroll
    for (int j = 0; j < 4; j++){ acc[i][j][0]=0.f; acc[i][j][1]=0.f; acc[i][j][2]=0.f; acc[i][j][3]=0.f; }

  for (int k0 = 0; k0 < 256; k0 += 64){
    __syncthreads();
    #pragma unroll
    for (int s4 = 0; s4 < 4; s4++){
      int s = w * 4 + s4;            // 0..31
      int sl = s & 15;
      int tile = sl >> 1, kk = sl & 1;
      const unsigned short* src = (s < 16)
          ? (A  + (size_t)(n0 + tile*16 + t16) * DIM + k0 + kk*32 + quad*8)
          : (Bm + (size_t)(o0 + tile*16 + t16) * DIM + k0 + kk*32 + quad*8);
      gload_lds16(src, (s < 16) ? (As + sl * 512) : (Bs + sl * 512));
    }
    __syncthreads();
    #pragma unroll
    for (int kk = 0; kk < 2; kk++){
      short8 a[2], bb[4];
      #pragma unroll
      for (int i = 0; i < 2; i++) a[i]  = *(const short8*)(As + ((wm*2 + i)*2 + kk) * 512 + l * 8);
      #pragma unroll
      for (int j = 0; j < 4; j++) bb[j] = *(const short8*)(Bs + ((wn*4 + j)*2 + kk) * 512 + l * 8);
      #pragma unroll
      for (int i = 0; i < 2; i++)
        #pragma unroll
        for (int j = 0; j < 4; j++)
          acc[i][j] = __builtin_amdgcn_mfma_f32_16x16x32_bf16(a[i], bb[j], acc[i][j], 0, 0, 0);
    }
  }

  // epilogue: out[o][n] = acc + bias[o] + x[o][n], per-lane float4 along n
  const float* xb = x + (size_t)b * DIM * NTOK;
  float* ob = out + (size_t)b * DIM * NTOK;
  #pragma unroll
  for (int j = 0; j < 4; j++){
    int o = o0 + wn*64 + j*16 + t16;
    float bias = bproj[o];
    #pragma unroll
    for (int i = 0; i < 2; i++){
      int n = n0 + wm*32 + i*16 + quad*4;
      float4 xv = *(const float4*)(xb + (size_t)o * NTOK + n);
      float4 res = { acc[i][j][0] + bias + xv.x,
                     acc[i][j][1] + bias + xv.y,
                     acc[i][j][2] + bias + xv.z,
                     acc[i][j][3] + bias + xv.w };
      *(float4*)(ob + (size_t)o * NTOK + n) = res;
    }
  }
}

extern "C" void kernel_launch(void* const* d_in, const int* in_sizes, int n_in,
                              void* d_out, int out_size, void* d_ws, size_t ws_size,
                              hipStream_t stream){
  const float* x     = (const float*)d_in[0];
  const float* wqkv  = (const float*)d_in[1];
  const float* wproj = (const float*)d_in[2];
  const float* bproj = (const float*)d_in[3];
  float* out = (float*)d_out;
  char* ws = (char*)d_ws;

  // ws layout (~82.4 MiB):
  unsigned short* xt   = (unsigned short*)(ws);                        // 32 MiB [b][n][256]
  unsigned short* qn   = (unsigned short*)(ws + ((size_t)32 << 20));   // 32 MiB [b][n][256]
  float* kvp           = (float*)(ws + ((size_t)64 << 20));            // 16 MiB [b][h][nt32][1024]
  unsigned short* M    = (unsigned short*)(ws + ((size_t)80 << 20));   // 2 MiB [b][256][256]
  unsigned short* wqbf = (unsigned short*)(ws + ((size_t)82 << 20));   // 384 KiB permuted

  k_transpose_x<<<dim3(64, 4, 16), 256, 0, stream>>>(x, xt);
  k_convert_w  <<<dim3(192), 256, 0, stream>>>(wqkv, wqbf);
  k_qkv5       <<<dim3(3072), 512, 0, stream>>>(wqbf, xt, qn, kvp);
  k_M          <<<dim3(8, 16), 256, 0, stream>>>(kvp, wproj, M);
  k_out5       <<<dim3(1024), 512, 0, stream>>>(M, qn, x, bproj, out);
}